// Round 11
// baseline (192.758 us; speedup 1.0000x reference)
//
#include <hip/hip_runtime.h>

#define NVOX 120000
#define KVOL 27
#define CH 64
#define TOTAL (NVOX * CH)
#define NF4 (TOTAL / 4)
#define EPSV 1e-5f

typedef __attribute__((ext_vector_type(8))) short bf16x8;
typedef __attribute__((ext_vector_type(4))) float f32x4;
typedef __attribute__((ext_vector_type(4))) unsigned int u32x4;

__device__ __forceinline__ unsigned short f2bf(float f) {
    unsigned int u = __builtin_bit_cast(unsigned int, f);
    u += 0x7FFFu + ((u >> 16) & 1u);          // RNE
    return (unsigned short)(u >> 16);
}

// ---- prep ------------------------------------------------------------------
// b <  432 : weight fp32 [k][c][d] -> bf16 MFMA-fragment order
//            wtf[(k*8+grp)*512 + lane*8 + j], grp=(d>>4)*2+(c>>5),
//            lane=((c&31)>>3)*16+(d&15), j=c&7   (validated rounds 4-8)
// b >= 432 : feats fp32 -> bf16, grid-stride float4
__global__ void prep(const float* __restrict__ w, unsigned short* __restrict__ wtf,
                     const float* __restrict__ f, unsigned short* __restrict__ fb,
                     float* __restrict__ stats) {
    const int b = blockIdx.x;
    const int tid = threadIdx.x;
    if (b < 432) {
        const int t = b * 256 + tid;               // t = k*4096 + c*64 + d (coalesced read)
        const int d = t & 63, c = (t >> 6) & 63, k = t >> 12;
        const int grp = (d >> 4) * 2 + (c >> 5);
        const int l = ((c & 31) >> 3) * 16 + (d & 15);
        const int j = c & 7;
        wtf[(((size_t)k * 8 + grp) * 64 + l) * 8 + j] = f2bf(w[t]);
        if (b == 0 && tid < 128) stats[tid] = 0.f;
    } else {
        for (int t = (b - 432) * 256 + tid; t < NF4; t += 1000 * 256) {
            const float4 x = ((const float4*)f)[t];
            ushort4 y;
            y.x = f2bf(x.x); y.y = f2bf(x.y); y.z = f2bf(x.z); y.w = f2bf(x.w);
            ((ushort4*)fb)[t] = y;
        }
    }
}

__device__ __forceinline__ void gatherRow(const unsigned short* __restrict__ fb,
                                          int idx, int q, bf16x8& a0, bf16x8& a1) {
    const int safe = idx < 0 ? 0 : idx;
    const unsigned short* row = fb + (size_t)safe * CH + q * 8;
    a0 = *(const bf16x8*)row;
    a1 = *(const bf16x8*)(row + 32);
    if (idx < 0) {
        a0 = (bf16x8)(short)0;
        a1 = (bf16x8)(short)0;
    }
}

// ---- conv: group-staged LDS weights + barrier-free inner k-loop ------------
// 32 voxels/wave, 938 blocks. W staged 6 slices (48KB) at a time: W line
// traffic is per-BLOCK (3.2M lines) instead of per-WAVE (11.6M, round 8's
// dominant TCP term). Only 2 barriers per group (10 total). Inside a group:
// round-8 pipeline (per-tile ballot skip, A gathered 1 slice ahead, idx 2
// ahead), B-frags read conflict-free from LDS.
__launch_bounds__(256, 4)
__global__ void conv_mfma(const unsigned short* __restrict__ featsB,
                          const unsigned short* __restrict__ WtF,
                          const int* __restrict__ nbr,
                          float* __restrict__ out,
                          float* __restrict__ stats) {
    __shared__ __align__(16) unsigned short ldsW[6 * 4096];   // 48KB: 6 slices
    __shared__ float lstats[128];
    const int tid = threadIdx.x;
    const int lane = tid & 63;
    const int m = lane & 15;
    const int q = lane >> 4;
    const int v0 = blockIdx.x * 128 + (tid >> 6) * 32;
    const int r0 = v0 + m;
    const int r1 = v0 + 16 + m;
    const bool ok0 = r0 < NVOX;
    const bool ok1 = r1 < NVOX;

    f32x4 acc[2][4];
#pragma unroll
    for (int t = 0; t < 2; ++t)
#pragma unroll
        for (int nt = 0; nt < 4; ++nt)
            acc[t][nt] = (f32x4){0.f, 0.f, 0.f, 0.f};
    if (tid < 128) lstats[tid] = 0.f;

    // A-pipeline prologue: gather slice 0, indices for slice 1
    int i0 = ok0 ? nbr[r0] : -1;
    int i1 = ok1 ? nbr[r1] : -1;
    unsigned long long m0 = __ballot(i0 >= 0);
    unsigned long long m1 = __ballot(i1 >= 0);
    bf16x8 a00, a01, a10, a11;
    if (m0) gatherRow(featsB, i0, q, a00, a01);
    if (m1) gatherRow(featsB, i1, q, a10, a11);
    int i0n = ok0 ? nbr[NVOX + r0] : -1;
    int i1n = ok1 ? nbr[NVOX + r1] : -1;

    int gstart = 0;
    for (int g = 0; g < 5; ++g) {
        const int S = (g == 4) ? 3 : 6;

        // stage group g's W slices into LDS (48KB / 24KB last)
        __syncthreads();                           // prev group reads done (g=0: lstats)
        {
            const unsigned short* src = WtF + (size_t)gstart * 4096;
            const int nchunk = S * 512;            // 16B chunks
            for (int c = tid; c < nchunk; c += 256)
                *(u32x4*)(&ldsW[c * 8]) = *(const u32x4*)(src + c * 8);
        }
        __syncthreads();

        for (int s = 0; s < S; ++s) {
            const int k = gstart + s;

            // masks + gather for slice k+1 (covered by this slice's compute)
            const unsigned long long m0n = __ballot(i0n >= 0);
            const unsigned long long m1n = __ballot(i1n >= 0);
            bf16x8 an00, an01, an10, an11;
            if (m0n) gatherRow(featsB, i0n, q, an00, an01);
            if (m1n) gatherRow(featsB, i1n, q, an10, an11);

            // prefetch indices for slice k+2
            int i0f = -1, i1f = -1;
            if (k + 2 < KVOL) {
                const int* nb = nbr + (size_t)(k + 2) * NVOX;
                i0f = ok0 ? nb[r0] : -1;
                i1f = ok1 ? nb[r1] : -1;
            }

            // compute slice k (B from LDS, conflict-free lane-contiguous b128)
            if (m0 | m1) {
                const unsigned short* wk = ldsW + s * 4096 + lane * 8;
                bf16x8 bfr[8];
#pragma unroll
                for (int h = 0; h < 8; ++h)
                    bfr[h] = *(const bf16x8*)(wk + h * 512);
                if (m0) {
#pragma unroll
                    for (int nt = 0; nt < 4; ++nt) {
                        acc[0][nt] = __builtin_amdgcn_mfma_f32_16x16x32_bf16(a00, bfr[nt * 2 + 0], acc[0][nt], 0, 0, 0);
                        acc[0][nt] = __builtin_amdgcn_mfma_f32_16x16x32_bf16(a01, bfr[nt * 2 + 1], acc[0][nt], 0, 0, 0);
                    }
                }
                if (m1) {
#pragma unroll
                    for (int nt = 0; nt < 4; ++nt) {
                        acc[1][nt] = __builtin_amdgcn_mfma_f32_16x16x32_bf16(a10, bfr[nt * 2 + 0], acc[1][nt], 0, 0, 0);
                        acc[1][nt] = __builtin_amdgcn_mfma_f32_16x16x32_bf16(a11, bfr[nt * 2 + 1], acc[1][nt], 0, 0, 0);
                    }
                }
            }

            // shift pipeline
            a00 = an00; a01 = an01; a10 = an10; a11 = an11;
            m0 = m0n; m1 = m1n;
            i0n = i0f; i1n = i1f;
        }
        gstart += S;
    }

    // ---- epilogue: guarded stores + block-reduced BN statistics ----
    // D layout: col = m (channel nt*16+m), row = q*4 + r (voxel within tile)
#pragma unroll
    for (int t = 0; t < 2; ++t) {
        const int rbase = v0 + t * 16 + q * 4;
        float* ob = out + (size_t)rbase * CH + m;
#pragma unroll
        for (int nt = 0; nt < 4; ++nt)
#pragma unroll
            for (int r = 0; r < 4; ++r)
                if (rbase + r < NVOX)
                    ob[(size_t)r * CH + nt * 16] = acc[t][nt][r];
    }

#pragma unroll
    for (int nt = 0; nt < 4; ++nt) {
        float s = 0.f, s2 = 0.f;
#pragma unroll
        for (int t = 0; t < 2; ++t)
#pragma unroll
            for (int r = 0; r < 4; ++r) {
                const float x = acc[t][nt][r];       // masked rows are exactly 0
                s += x;
                s2 = fmaf(x, x, s2);
            }
        s  += __shfl_xor(s, 16);  s  += __shfl_xor(s, 32);
        s2 += __shfl_xor(s2, 16); s2 += __shfl_xor(s2, 32);
        if (lane < 16) {
            atomicAdd(&lstats[nt * 16 + m], s);
            atomicAdd(&lstats[64 + nt * 16 + m], s2);
        }
    }
    __syncthreads();
    if (tid < 128) atomicAdd(&stats[tid], lstats[tid]);
}

// ---- bn_relu: grid-stride with inline finalize -----------------------------
__launch_bounds__(256)
__global__ void bn_relu(float* __restrict__ out, const float* __restrict__ stats,
                        const float* __restrict__ gamma, const float* __restrict__ beta) {
    __shared__ float sb[128];
    const int tid = threadIdx.x;
    if (tid < 64) {
        const float inv_n = 1.0f / (float)NVOX;
        const float mean = stats[tid] * inv_n;
        const float var = stats[64 + tid] * inv_n - mean * mean;
        const float sc = gamma[tid] * rsqrtf(var + EPSV);
        sb[tid] = sc;
        sb[64 + tid] = beta[tid] - mean * sc;
    }
    __syncthreads();
    float4* o4 = (float4*)out;
    for (int e = blockIdx.x * 256 + tid; e < NF4; e += 960 * 256) {
        float4 x = o4[e];
        const int cb = (e & 15) * 4;
        x.x = fmaxf(fmaf(x.x, sb[cb + 0], sb[64 + cb + 0]), 0.f);
        x.y = fmaxf(fmaf(x.y, sb[cb + 1], sb[64 + cb + 1]), 0.f);
        x.z = fmaxf(fmaf(x.z, sb[cb + 2], sb[64 + cb + 2]), 0.f);
        x.w = fmaxf(fmaf(x.w, sb[cb + 3], sb[64 + cb + 3]), 0.f);
        o4[e] = x;
    }
}

extern "C" void kernel_launch(void* const* d_in, const int* in_sizes, int n_in,
                              void* d_out, int out_size, void* d_ws, size_t ws_size,
                              hipStream_t stream) {
    const float* feats  = (const float*)d_in[0];   // [N, 64]
    const float* weight = (const float*)d_in[1];   // [27, 64, 64]
    const float* gamma  = (const float*)d_in[2];   // [64]
    const float* beta   = (const float*)d_in[3];   // [64]
    const int*   nbr    = (const int*)d_in[4];     // [27, N]
    float* out = (float*)d_out;                    // [N, 64]

    // ws layout: [0,512) stats; [512, 512+221184) WtF bf16 frag-order; then featsB
    float* stats = (float*)d_ws;
    unsigned short* WtF    = (unsigned short*)((char*)d_ws + 512);
    unsigned short* featsB = (unsigned short*)((char*)d_ws + 512 + 221184);

    prep<<<432 + 1000, 256, 0, stream>>>(weight, WtF, feats, featsB, stats);
    conv_mfma<<<(NVOX + 127) / 128, 256, 0, stream>>>(featsB, WtF, nbr, out, stats);
    bn_relu<<<960, 256, 0, stream>>>(out, stats, gamma, beta);
}